// Round 1
// baseline (1504.501 us; speedup 1.0000x reference)
//
#include <hip/hip_runtime.h>

#define HID 64

// ---------------------------------------------------------------------------
// Layout: lanes = nodes. Each wave owns 3 clusters = 60 nodes (lanes 0..59).
// Per-wave LDS act matrix: 60 rows x 65 floats (stride 65 -> (lane+k)%32
// distinct banks, 2 lanes/bank = free). Weights are wave-uniform -> s_load.
// ---------------------------------------------------------------------------

__device__ __forceinline__ void ln_relu_store(float* Arow, float* acc,
                                              const float* __restrict__ g,
                                              const float* __restrict__ be) {
  float mu = 0.f;
#pragma unroll
  for (int f = 0; f < HID; ++f) mu += acc[f];
  mu *= (1.0f / HID);
  float vs = 0.f;
#pragma unroll
  for (int f = 0; f < HID; ++f) { float d = acc[f] - mu; vs = fmaf(d, d, vs); }
  vs *= (1.0f / HID);
  const float rs = rsqrtf(vs + 1e-5f);
#pragma unroll
  for (int f = 0; f < HID; ++f) {
    float h = (acc[f] - mu) * rs * g[f] + be[f];
    Arow[f] = fmaxf(h, 0.f);   // ReLU, store h row for next matmul's k-reads
  }
}

template <int KDIM, int FDIM>
__device__ __forceinline__ void matvec(const float* Arow,
                                       const float* __restrict__ W,
                                       const float* __restrict__ b,
                                       float* acc) {
#pragma unroll
  for (int f = 0; f < FDIM; ++f) acc[f] = b[f];
#pragma unroll 2
  for (int k = 0; k < KDIM; ++k) {
    const float a = Arow[k];                 // per-lane LDS read, conflict-free
#pragma unroll
    for (int f = 0; f < FDIM; ++f)           // W uniform -> SGPR operand fmac
      acc[f] = fmaf(a, W[k * FDIM + f], acc[f]);
  }
}

// One subgraph layer: h = MLP(out) [64->64 LN relu ->32]; pooled = segmax(h);
// out = concat([h, pooled]).
__device__ __forceinline__ void layer_step(float* A, float* P, int rowoff,
                                           bool active, int lane, int mycl,
                                           int waveCluster, int C,
                                           const float* __restrict__ w1,
                                           const float* __restrict__ b1,
                                           const float* __restrict__ g,
                                           const float* __restrict__ be,
                                           const float* __restrict__ w2,
                                           const float* __restrict__ b2) {
  if (active) {
    float acc[HID];
    matvec<HID, HID>(A + rowoff, w1, b1, acc);
    ln_relu_store(A + rowoff, acc, g, be);
    float h2[32];
    matvec<HID, 32>(A + rowoff, w2, b2, h2);
#pragma unroll
    for (int j = 0; j < 32; ++j) A[rowoff + j] = h2[j];   // h -> cols 0..31
  }
  __syncthreads();
  // pool: 3 clusters x 32 feats = 96 items; chunk0 = lanes 0..63, chunk1 = lanes 0..31
  {
    const int cl = lane >> 5, j = lane & 31;
    if (waveCluster + cl < C) {
      float m = -3.4e38f;
#pragma unroll
      for (int r = 0; r < 20; ++r) m = fmaxf(m, A[(cl * 20 + r) * 65 + j]);
      P[cl * 36 + j] = m;
    }
    if (lane < 32 && (waveCluster + 2 < C)) {
      float m = -3.4e38f;
#pragma unroll
      for (int r = 0; r < 20; ++r) m = fmaxf(m, A[(40 + r) * 65 + lane]);
      P[2 * 36 + lane] = m;
    }
  }
  __syncthreads();
  if (active) {
#pragma unroll
    for (int j = 0; j < 32; ++j) A[rowoff + 32 + j] = P[mycl * 36 + j];
  }
  __syncthreads();
}

__global__ void __launch_bounds__(256, 2)
kA(const float* __restrict__ x,
   const float* __restrict__ pw1, const float* __restrict__ pb1,
   const float* __restrict__ pg,  const float* __restrict__ pbe,
   const float* __restrict__ pw2, const float* __restrict__ pb2,
   const float* __restrict__ w1a, const float* __restrict__ b1a,
   const float* __restrict__ ga,  const float* __restrict__ bea,
   const float* __restrict__ w2a, const float* __restrict__ b2a,
   const float* __restrict__ w1b, const float* __restrict__ b1b,
   const float* __restrict__ gb,  const float* __restrict__ beb,
   const float* __restrict__ w2b, const float* __restrict__ b2b,
   const float* __restrict__ w1c, const float* __restrict__ b1c,
   const float* __restrict__ gc,  const float* __restrict__ bec,
   const float* __restrict__ w2c, const float* __restrict__ b2c,
   float* __restrict__ ws, int C) {
  __shared__ float act[4][60 * 65];
  __shared__ float pool[4][108];
  const int lane = threadIdx.x & 63;
  const int w = threadIdx.x >> 6;
  const int waveCluster = blockIdx.x * 12 + w * 3;
  float* A = act[w];
  float* P = pool[w];
  const int mycl = lane / 20;                       // 0..3 (3 only for idle lanes)
  const bool active = (lane < 60) && (waveCluster + mycl < C);
  const int rowoff = lane * 65;

  if (active) {
    const int node = waveCluster * 20 + lane;
    const float4* xr = (const float4*)(x + (long)node * 16);
    float4 v0 = xr[0], v1 = xr[1], v2 = xr[2], v3 = xr[3];
    A[rowoff + 0]  = v0.x; A[rowoff + 1]  = v0.y; A[rowoff + 2]  = v0.z; A[rowoff + 3]  = v0.w;
    A[rowoff + 4]  = v1.x; A[rowoff + 5]  = v1.y; A[rowoff + 6]  = v1.z; A[rowoff + 7]  = v1.w;
    A[rowoff + 8]  = v2.x; A[rowoff + 9]  = v2.y; A[rowoff + 10] = v2.z; A[rowoff + 11] = v2.w;
    A[rowoff + 12] = v3.x; A[rowoff + 13] = v3.y; A[rowoff + 14] = v3.z; A[rowoff + 15] = v3.w;
    // pre-MLP: 16 -> 64 (LN, relu) -> 64
    float acc[HID];
    matvec<16, HID>(A + rowoff, pw1, pb1, acc);
    ln_relu_store(A + rowoff, acc, pg, pbe);
    float acc2[HID];
    matvec<HID, HID>(A + rowoff, pw2, pb2, acc2);
#pragma unroll
    for (int f = 0; f < HID; ++f) A[rowoff + f] = acc2[f];
  }
  __syncthreads();

  layer_step(A, P, rowoff, active, lane, mycl, waveCluster, C, w1a, b1a, ga, bea, w2a, b2a);
  layer_step(A, P, rowoff, active, lane, mycl, waveCluster, C, w1b, b1b, gb, beb, w2b, b2b);
  layer_step(A, P, rowoff, active, lane, mycl, waveCluster, C, w1c, b1c, gc, bec, w2c, b2c);

  // final per-cluster max over all 64 features -> ws[C][64] (coalesced)
#pragma unroll
  for (int p = 0; p < 3; ++p) {
    const int gcl = waveCluster + p;
    if (gcl < C) {
      float m = -3.4e38f;
#pragma unroll
      for (int r = 0; r < 20; ++r) m = fmaxf(m, A[(p * 20 + r) * 65 + lane]);
      ws[(long)gcl * 64 + lane] = m;
    }
  }
}

// Output MLP over C cluster rows: 64 -> 64 (LN, relu) -> 128, L2-normalize.
// Also writes batch_out (as float) at d_out + C*128.
__global__ void __launch_bounds__(128, 2)
kB(const float* __restrict__ ws, const int* __restrict__ batch,
   const float* __restrict__ ow1, const float* __restrict__ ob1,
   const float* __restrict__ og,  const float* __restrict__ obe,
   const float* __restrict__ ow2, const float* __restrict__ ob2,
   float* __restrict__ out, int C) {
  __shared__ float buf[2][64 * 65];
  const int lane = threadIdx.x & 63;
  const int w = threadIdx.x >> 6;
  float* Brow = buf[w] + lane * 65;
  const long r = (long)(blockIdx.x * 2 + w) * 64 + lane;
  if (r < C) {
    const float4* src = (const float4*)(ws + r * 64);
#pragma unroll
    for (int q = 0; q < 16; ++q) {
      float4 v = src[q];
      Brow[q * 4 + 0] = v.x; Brow[q * 4 + 1] = v.y;
      Brow[q * 4 + 2] = v.z; Brow[q * 4 + 3] = v.w;
    }
    float acc[HID];
    matvec<HID, HID>(Brow, ow1, ob1, acc);
    ln_relu_store(Brow, acc, og, obe);
    float o[128];
    matvec<HID, 128>(Brow, ow2, ob2, o);
    float n2 = 0.f;
#pragma unroll
    for (int f = 0; f < 128; ++f) n2 = fmaf(o[f], o[f], n2);
    const float s = 1.0f / fmaxf(sqrtf(n2), 1e-12f);
    float4* dst = (float4*)(out + r * 128);
#pragma unroll
    for (int q = 0; q < 32; ++q) {
      float4 v = { o[q * 4] * s, o[q * 4 + 1] * s, o[q * 4 + 2] * s, o[q * 4 + 3] * s };
      dst[q] = v;
    }
    out[(long)C * 128 + r] = (float)batch[r * 20];
  }
}

extern "C" void kernel_launch(void* const* d_in, const int* in_sizes, int n_in,
                              void* d_out, int out_size, void* d_ws, size_t ws_size,
                              hipStream_t stream) {
  const float* x    = (const float*)d_in[0];
  const int*   batch = (const int*)d_in[2];
  const float* pw1 = (const float*)d_in[3];
  const float* pb1 = (const float*)d_in[4];
  const float* pg  = (const float*)d_in[5];
  const float* pbe = (const float*)d_in[6];
  const float* pw2 = (const float*)d_in[7];
  const float* pb2 = (const float*)d_in[8];
  const float* w1a = (const float*)d_in[9];
  const float* b1a = (const float*)d_in[10];
  const float* ga  = (const float*)d_in[11];
  const float* bea = (const float*)d_in[12];
  const float* w2a = (const float*)d_in[13];
  const float* b2a = (const float*)d_in[14];
  const float* w1b = (const float*)d_in[15];
  const float* b1b = (const float*)d_in[16];
  const float* gb  = (const float*)d_in[17];
  const float* beb = (const float*)d_in[18];
  const float* w2b = (const float*)d_in[19];
  const float* b2b = (const float*)d_in[20];
  const float* w1c = (const float*)d_in[21];
  const float* b1c = (const float*)d_in[22];
  const float* gc  = (const float*)d_in[23];
  const float* bec = (const float*)d_in[24];
  const float* w2c = (const float*)d_in[25];
  const float* b2c = (const float*)d_in[26];
  const float* ow1 = (const float*)d_in[27];
  const float* ob1 = (const float*)d_in[28];
  const float* og  = (const float*)d_in[29];
  const float* obe = (const float*)d_in[30];
  const float* ow2 = (const float*)d_in[31];
  const float* ob2 = (const float*)d_in[32];

  const int N = in_sizes[0] / 16;
  const int C = N / 20;
  float* ws  = (float*)d_ws;
  float* out = (float*)d_out;

  const int blocksA = (C + 11) / 12;   // 12 clusters per block (4 waves x 3)
  hipLaunchKernelGGL(kA, dim3(blocksA), dim3(256), 0, stream,
                     x, pw1, pb1, pg, pbe, pw2, pb2,
                     w1a, b1a, ga, bea, w2a, b2a,
                     w1b, b1b, gb, beb, w2b, b2b,
                     w1c, b1c, gc, bec, w2c, b2c,
                     ws, C);

  const int blocksB = (C + 127) / 128; // 128 rows per block (2 waves x 64)
  hipLaunchKernelGGL(kB, dim3(blocksB), dim3(128), 0, stream,
                     ws, batch, ow1, ob1, og, obe, ow2, ob2, out, C);
}